// Round 7
// baseline (1715.073 us; speedup 1.0000x reference)
//
#include <hip/hip_runtime.h>
#include <hip/hip_cooperative_groups.h>
#include <math.h>

namespace cg = cooperative_groups;

// Problem constants
#define BB 16
#define TT 2048
#define DD 512
#define WW 12
#define TQ 512
#define NROWS (BB * TQ)

typedef _Float16 f16;
typedef __attribute__((ext_vector_type(8))) _Float16 f16x8;
typedef __attribute__((ext_vector_type(4))) _Float16 f16x4;
typedef __attribute__((ext_vector_type(4))) float f32x4;

#define MFMA16(a, b, c) __builtin_amdgcn_mfma_f32_16x16x32_f16((a), (b), (c), 0, 0, 0)

// ws layout
#define WS_IDS  0u
#define WS_W16  (512u * 1024u)              // 3072 x 512 f16 = 3 MB ([w_ih ; w_hh])
#define WS_H16  (4u * 1024u * 1024u)        // 8192 x 512 f16 = 8 MB (ping)
#define WS_GI   (12u * 1024u * 1024u)       // 32768 x 1536 f16 = 96 MB

__device__ __forceinline__ float fsigm(float v) { return 1.0f / (1.0f + __expf(-v)); }
__device__ __forceinline__ float ftanh(float v) {
    float a = fabsf(v);
    float t = __expf(-2.0f * a);
    float r = (1.0f - t) / (1.0f + t);
    return copysignf(r, v);
}

__device__ __forceinline__ f16x8 cvt8(float4 a, float4 b) {
    f16x8 r;
    r[0] = (_Float16)a.x; r[1] = (_Float16)a.y; r[2] = (_Float16)a.z; r[3] = (_Float16)a.w;
    r[4] = (_Float16)b.x; r[5] = (_Float16)b.y; r[6] = (_Float16)b.z; r[7] = (_Float16)b.w;
    return r;
}

// -------- Kernel 1: band top-k selection (round-5, proven) ------------------
__global__ __launch_bounds__(256) void select_topk_kernel(
    const float* __restrict__ x, int* __restrict__ ids)
{
    const int tid = threadIdx.x, wid = tid >> 6, lane = tid & 63;
    const int bid = blockIdx.x;
    const int swz = (bid & 7) * 256 + (bid >> 3);
    const int n = swz * 4 + wid;
    const int b = n >> 9, qi = n & 511;

    int t = (qi == TQ - 1) ? (TT - 1)
          : (int)((double)qi * ((double)(TT - 1) / (double)(TQ - 1)));
    int j0 = t - (WW - 1); if (j0 < 0) j0 = 0;
    int j1 = t + (WW - 1); if (j1 > TT - 1) j1 = TT - 1;
    const int ncand = j1 - j0 + 1;

    const int c = lane & 3, i = lane >> 2;
    const float* qrow = x + ((size_t)b * TT + t) * DD + i * 4;

    float4 q[8];
#pragma unroll
    for (int it = 0; it < 8; ++it) q[it] = *(const float4*)(qrow + it * 64);

    double s[6];
#pragma unroll
    for (int r = 0; r < 6; ++r) {
        int cc = r * 4 + c;
        double s0 = 0.0, s1 = 0.0;
        if (cc < ncand) {
            const float* krow = x + ((size_t)b * TT + (j0 + cc)) * DD + i * 4;
#pragma unroll
            for (int it = 0; it < 8; ++it) {
                float4 kv = *(const float4*)(krow + it * 64);
                s0 = fma((double)q[it].x, (double)kv.x, s0);
                s1 = fma((double)q[it].y, (double)kv.y, s1);
                s0 = fma((double)q[it].z, (double)kv.z, s0);
                s1 = fma((double)q[it].w, (double)kv.w, s1);
            }
        }
        double sv = s0 + s1;
        sv += __shfl_xor(sv, 4);
        sv += __shfl_xor(sv, 8);
        sv += __shfl_xor(sv, 16);
        sv += __shfl_xor(sv, 32);
        s[r] = sv;
    }

    const int rr = lane >> 2;
    double sj = s[0];
    sj = (rr == 1) ? s[1] : sj;
    sj = (rr == 2) ? s[2] : sj;
    sj = (rr == 3) ? s[3] : sj;
    sj = (rr == 4) ? s[4] : sj;
    sj = (rr == 5) ? s[5] : sj;
    bool valid = lane < ncand;
    if (!valid) sj = -1.0e300;

    int rank = 0;
    for (int kk = 0; kk < 2 * WW - 1; ++kk) {
        if (kk >= ncand) break;
        double bs = __shfl(sj, kk);
        rank += (bs > sj || (bs == sj && kk < lane)) ? 1 : 0;
    }
    bool sel = valid && (rank < WW);
    unsigned long long m = __ballot(sel);
    if (sel) {
        int pos = __popcll(m & ((1ull << lane) - 1ull));
        ids[(size_t)n * WW + pos] = j0 + lane;
    }
}

// -------- Kernel 2: f32 -> f16 weight conversion ---------------------------
__global__ __launch_bounds__(256) void convert_w_kernel(
    const float* __restrict__ wi, const float* __restrict__ wh, f16* __restrict__ w16)
{
    const int PER = 3 * DD * DD / 4;
    int i = blockIdx.x * 256 + threadIdx.x;
    float4 v;
    if (i < PER) v = ((const float4*)wi)[i];
    else         v = ((const float4*)wh)[i - PER];
    f16x4 o;
    o[0] = (_Float16)v.x; o[1] = (_Float16)v.y; o[2] = (_Float16)v.z; o[3] = (_Float16)v.w;
    *(f16x4*)(w16 + (size_t)i * 4) = o;
}

// -------- Kernel 3: GI = x @ w_ih.T + b_ih, m97-geometry -------------------
// 256 thr / 4 waves; tile 128 rows x 128 cols; BK = 64 (two 32-k halves,
// each half uses the proven [entity][4 slot x 16B] XOR-swizzled layout).
// Grid 3072 = 8 xcd x (32 rb x 12 cb). 8 K-phases, 32 MFMA/wave/phase.
__global__ __launch_bounds__(256, 2) void gi_gemm_kernel(
    const float* __restrict__ x,
    const f16* __restrict__ w16,        // rows 0..1535 = w_ih
    const float* __restrict__ b_ih,
    f16* __restrict__ gi)               // [32768][1536]
{
    __shared__ __align__(16) char sB[2][16 * 1024];
    __shared__ __align__(16) char sX[2][16 * 1024];

    const int tid = threadIdx.x;
    const int lane = tid & 63, wid = tid >> 6;
    const int wm = wid >> 1, wn = wid & 1;
    const int l15 = lane & 15, lhi = lane >> 4;
    const int bid = blockIdx.x;
    const int xcd = bid & 7, idx = bid >> 3;       // 0..383
    const int rb = xcd * 32 + idx / 12;
    const int cb = idx % 12;
    const int row0 = rb * 128, c0 = cb * 128;

    // B staging: 4 chunks/wave (16 total; 1KB = 16 cols x 4 slots, per half)
    const int slot = lane & 3, lc = lane >> 2;
    const f16* bsrc[4]; int bdst[4];
#pragma unroll
    for (int ii = 0; ii < 4; ++ii) {
        int ch = wid * 4 + ii;                     // 0..15
        int half = ch >> 3, cg = ch & 7;
        int col = cg * 16 + lc;
        bsrc[ii] = w16 + ((size_t)(c0 + col) * 512 + half * 32
                          + (size_t)((slot ^ ((col >> 1) & 3)) * 8));
        bdst[ii] = half * 8192 + cg * 1024;
    }

    // X staging (reg path): 2 lanes/row; each covers both halves
    const int xrow = tid >> 1, bsel = tid & 1;
    const int cA = (2 * bsel) ^ ((xrow >> 1) & 3);
    const float* xsrc = x + (size_t)(row0 + xrow) * DD;
    const float* xp0 = xsrc + cA * 8;
    const float* xp1 = xsrc + (cA ^ 1) * 8;
    const int xw0 = xrow * 64 + (2 * bsel) * 16;

    const int swzo = (lhi ^ ((l15 >> 1) & 3)) * 16;
    const int aBase = (wm * 64 + l15) * 64 + swzo;     // + h*8192 + mf*1024
    const int bBase = (wn * 64 + l15) * 64 + swzo;     // + h*8192 + nf*1024

    f32x4 acc[4][4];
#pragma unroll
    for (int mf = 0; mf < 4; ++mf)
#pragma unroll
        for (int nf = 0; nf < 4; ++nf) { f32x4 z = {0.f,0.f,0.f,0.f}; acc[mf][nf] = z; }

    // prologue: fill buffer 0 (k0 = 0)
    {
#pragma unroll
        for (int ii = 0; ii < 4; ++ii)
            __builtin_amdgcn_global_load_lds(
                (const __attribute__((address_space(1))) unsigned*)bsrc[ii],
                (__attribute__((address_space(3))) unsigned*)(&sB[0][0] + bdst[ii]), 16, 0, 0);
#pragma unroll
        for (int h = 0; h < 2; ++h) {
            float4 a0 = *(const float4*)(xp0 + h * 32);
            float4 a1 = *(const float4*)(xp0 + h * 32 + 4);
            float4 a2 = *(const float4*)(xp1 + h * 32);
            float4 a3 = *(const float4*)(xp1 + h * 32 + 4);
            *(f16x8*)(&sX[0][0] + h * 8192 + xw0)      = cvt8(a0, a1);
            *(f16x8*)(&sX[0][0] + h * 8192 + xw0 + 16) = cvt8(a2, a3);
        }
    }

    int cur = 0;
    for (int ks = 0; ks < 8; ++ks) {
        asm volatile("s_waitcnt vmcnt(0)" ::: "memory");
        __syncthreads();

        const int kn = (ks + 1) * 64;
        float4 a[2][4];
        if (ks < 7) {
#pragma unroll
            for (int ii = 0; ii < 4; ++ii)
                __builtin_amdgcn_global_load_lds(
                    (const __attribute__((address_space(1))) unsigned*)(bsrc[ii] + kn),
                    (__attribute__((address_space(3))) unsigned*)(&sB[cur ^ 1][0] + bdst[ii]), 16, 0, 0);
#pragma unroll
            for (int h = 0; h < 2; ++h) {
                a[h][0] = *(const float4*)(xp0 + kn + h * 32);
                a[h][1] = *(const float4*)(xp0 + kn + h * 32 + 4);
                a[h][2] = *(const float4*)(xp1 + kn + h * 32);
                a[h][3] = *(const float4*)(xp1 + kn + h * 32 + 4);
            }
        }

#pragma unroll
        for (int h = 0; h < 2; ++h) {
            f16x8 ax[4];
#pragma unroll
            for (int mf = 0; mf < 4; ++mf)
                ax[mf] = *(const f16x8*)(&sX[cur][0] + h * 8192 + aBase + mf * 1024);
#pragma unroll
            for (int nf = 0; nf < 4; ++nf) {
                f16x8 Bv = *(const f16x8*)(&sB[cur][0] + h * 8192 + bBase + nf * 1024);
#pragma unroll
                for (int mf = 0; mf < 4; ++mf)
                    acc[mf][nf] = MFMA16(ax[mf], Bv, acc[mf][nf]);
            }
        }

        if (ks < 7) {
#pragma unroll
            for (int h = 0; h < 2; ++h) {
                *(f16x8*)(&sX[cur ^ 1][0] + h * 8192 + xw0)      = cvt8(a[h][0], a[h][1]);
                *(f16x8*)(&sX[cur ^ 1][0] + h * 8192 + xw0 + 16) = cvt8(a[h][2], a[h][3]);
            }
        }
        cur ^= 1;
    }

#pragma unroll
    for (int nf = 0; nf < 4; ++nf) {
        int col = c0 + wn * 64 + nf * 16 + l15;
        float bi = b_ih[col];
#pragma unroll
        for (int mf = 0; mf < 4; ++mf)
#pragma unroll
            for (int r = 0; r < 4; ++r) {
                int row = row0 + wm * 64 + mf * 16 + lhi * 4 + r;
                gi[(size_t)row * 1536 + col] = (f16)(acc[mf][nf][r] + bi);
            }
    }
}

// -------- Kernel 4: step 0 elementwise (h0 = 0) ----------------------------
__global__ __launch_bounds__(256) void step0_kernel(
    const int* __restrict__ ids, const f16* __restrict__ gi,
    const float* __restrict__ b_hh, f16* __restrict__ h16w)
{
    int g = blockIdx.x * 256 + threadIdx.x;
    int row = g >> 6;
    int c8 = (g & 63) * 8;
    int src = (row >> 9) * TT + ids[(size_t)row * WW + 0];
    const f16* gr = gi + (size_t)src * 1536 + c8;
    f16x8 vr = *(const f16x8*)(gr);
    f16x8 vz = *(const f16x8*)(gr + 512);
    f16x8 vn = *(const f16x8*)(gr + 1024);
    f16x8 out;
#pragma unroll
    for (int j = 0; j < 8; ++j) {
        int col = c8 + j;
        float R = fsigm((float)vr[j] + b_hh[col]);
        float Z = fsigm((float)vz[j] + b_hh[DD + col]);
        float N = ftanh((float)vn[j] + R * b_hh[2 * DD + col]);
        out[j] = (f16)((1.0f - Z) * N);
    }
    *(f16x8*)(h16w + (size_t)row * DD + c8) = out;
}

// -------- Shared per-step GRU body (h-side only), used by both paths -------
struct StepCtx {
    const f16* bsrc[3]; int bdst[3];
    int aA0, colb[2];
    int row0, c0;
    int wm, wn, l15, lhi, tid, lane, wid;
};

// -------- Kernel 5a: FUSED cooperative 11-step GRU -------------------------
// 512 blocks x 256 thr (2 blocks/CU, exactly resident). Per step: identical
// body to the proven round-6 gru_step_h_kernel; grid sync between steps.
__global__ __launch_bounds__(256, 2) void gru_steps_fused_kernel(
    const int* __restrict__ ids,
    const f16* __restrict__ w16,
    const float* __restrict__ b_hh,
    const f16* __restrict__ gi,
    f16* __restrict__ P0,
    f16* __restrict__ P1,
    float* __restrict__ f32out)
{
    cg::grid_group grid = cg::this_grid();

    __shared__ __align__(16) char sB[2][12 * 1024];
    __shared__ __align__(16) char sH[2][8 * 1024];
    __shared__ int sXrow[128];

    const int tid = threadIdx.x;
    const int lane = tid & 63, wid = tid >> 6;
    const int wm = wid >> 1, wn = wid & 1;
    const int l15 = lane & 15, lhi = lane >> 4;
    const int bid = blockIdx.x;
    const int xcd = bid & 7, idx = bid >> 3;
    const int rb = xcd * 8 + (idx & 7);
    const int cb = idx >> 3;
    const int row0 = rb * 128, c0 = cb * 64;

    // invariant staging pointers (w_hh)
    const int slot = lane & 3, lc = lane >> 2;
    const f16* bsrc[3]; int bdst[3];
#pragma unroll
    for (int ii = 0; ii < 3; ++ii) {
        int ch = wid * 3 + ii;
        int gg = ch >> 2, cg2 = ch & 3;
        int col = cg2 * 16 + lc;
        bsrc[ii] = w16 + ((size_t)(1536 + gg * 512 + c0 + col) * 512
                          + (size_t)((slot ^ ((col >> 1) & 3)) * 8));
        bdst[ii] = ch * 1024;
    }

    const int swzo = (lhi ^ ((l15 >> 1) & 3)) * 16;
    const int aA0 = (wm * 64 + l15) * 64 + swzo;
    int colb[2];
#pragma unroll
    for (int nf = 0; nf < 2; ++nf)
        colb[nf] = (wn * 32 + nf * 16 + l15) * 64 + swzo;

    for (int s = 1; s < WW; ++s) {
        const f16* h16r = (s & 1) ? P0 : P1;
        f16* h16w      = (s == WW - 1) ? nullptr : ((s & 1) ? P1 : P0);
        float* f32w    = (s == WW - 1) ? f32out : nullptr;

        if (tid < 128) {
            int nn = row0 + tid;
            sXrow[tid] = (nn >> 9) * TT + ids[(size_t)nn * WW + s];
        }

        const f16* hsrc[2]; int hdst[2];
#pragma unroll
        for (int ii = 0; ii < 2; ++ii) {
            int ch = wid * 2 + ii;
            int hrow = ch * 16 + lc;
            hsrc[ii] = h16r + ((size_t)(row0 + hrow) * 512
                               + (size_t)((slot ^ ((lc >> 1) & 3)) * 8));
            hdst[ii] = ch * 1024;
        }

        f32x4 accR[4][2], accZ[4][2], accHN[4][2];
#pragma unroll
        for (int mf = 0; mf < 4; ++mf)
#pragma unroll
            for (int nf = 0; nf < 2; ++nf) {
                f32x4 z = {0.f, 0.f, 0.f, 0.f};
                accR[mf][nf] = z; accZ[mf][nf] = z; accHN[mf][nf] = z;
            }

        // prologue: fill buffer 0
#pragma unroll
        for (int ii = 0; ii < 3; ++ii)
            __builtin_amdgcn_global_load_lds(
                (const __attribute__((address_space(1))) unsigned*)bsrc[ii],
                (__attribute__((address_space(3))) unsigned*)(&sB[0][0] + bdst[ii]), 16, 0, 0);
#pragma unroll
        for (int ii = 0; ii < 2; ++ii)
            __builtin_amdgcn_global_load_lds(
                (const __attribute__((address_space(1))) unsigned*)hsrc[ii],
                (__attribute__((address_space(3))) unsigned*)(&sH[0][0] + hdst[ii]), 16, 0, 0);

        int cur = 0;
        for (int ks = 0; ks < 16; ++ks) {
            asm volatile("s_waitcnt vmcnt(0)" ::: "memory");
            __syncthreads();

            const int kn = (ks + 1) * 32;
            if (ks < 15) {
#pragma unroll
                for (int ii = 0; ii < 3; ++ii)
                    __builtin_amdgcn_global_load_lds(
                        (const __attribute__((address_space(1))) unsigned*)(bsrc[ii] + kn),
                        (__attribute__((address_space(3))) unsigned*)(&sB[cur ^ 1][0] + bdst[ii]), 16, 0, 0);
#pragma unroll
                for (int ii = 0; ii < 2; ++ii)
                    __builtin_amdgcn_global_load_lds(
                        (const __attribute__((address_space(1))) unsigned*)(hsrc[ii] + kn),
                        (__attribute__((address_space(3))) unsigned*)(&sH[cur ^ 1][0] + hdst[ii]), 16, 0, 0);
            }

            f16x8 ah[4];
#pragma unroll
            for (int mf = 0; mf < 4; ++mf)
                ah[mf] = *(const f16x8*)(&sH[cur][0] + aA0 + mf * 1024);

#pragma unroll
            for (int nf = 0; nf < 2; ++nf) {
                const char* bb = &sB[cur][0] + colb[nf];
                f16x8 B0 = *(const f16x8*)(bb + 0 * 4096);
                f16x8 B1 = *(const f16x8*)(bb + 1 * 4096);
                f16x8 B2 = *(const f16x8*)(bb + 2 * 4096);
#pragma unroll
                for (int mf = 0; mf < 4; ++mf) {
                    accR[mf][nf]  = MFMA16(ah[mf], B0, accR[mf][nf]);
                    accZ[mf][nf]  = MFMA16(ah[mf], B1, accZ[mf][nf]);
                    accHN[mf][nf] = MFMA16(ah[mf], B2, accHN[mf][nf]);
                }
            }
            cur ^= 1;
        }

        // epilogue: gather GI, gates, state update
#pragma unroll
        for (int nf = 0; nf < 2; ++nf) {
            int col = c0 + wn * 32 + nf * 16 + l15;
            float bhr = b_hh[col];
            float bhz = b_hh[DD + col];
            float bhn = b_hh[2 * DD + col];
#pragma unroll
            for (int mf = 0; mf < 4; ++mf) {
#pragma unroll
                for (int r = 0; r < 4; ++r) {
                    int row = row0 + wm * 64 + mf * 16 + lhi * 4 + r;
                    size_t off = (size_t)row * DD + col;
                    int src = sXrow[row - row0];
                    const f16* gr = gi + (size_t)src * 1536 + col;
                    float gir = (float)gr[0];
                    float giz = (float)gr[512];
                    float gin = (float)gr[1024];
                    float hold = (float)h16r[off];
                    float R = fsigm(gir + accR[mf][nf][r] + bhr);
                    float Z = fsigm(giz + accZ[mf][nf][r] + bhz);
                    float N = ftanh(gin + R * (accHN[mf][nf][r] + bhn));
                    float res = (1.0f - Z) * N + Z * hold;
                    if (h16w) h16w[off] = (f16)res;
                    if (f32w) f32w[off] = res;
                }
            }
        }

        if (s < WW - 1) {
            __threadfence();
            grid.sync();
        }
    }
}

// -------- Kernel 5b: fallback single-step (round-6 proven) -----------------
__global__ __launch_bounds__(256, 2) void gru_step_h_kernel(
    const int* __restrict__ ids,
    const f16* __restrict__ w16,
    const float* __restrict__ b_hh,
    const f16* __restrict__ gi,
    const f16* __restrict__ h16r,
    f16* __restrict__ h16w,
    float* __restrict__ f32w,
    int step)
{
    __shared__ __align__(16) char sB[2][12 * 1024];
    __shared__ __align__(16) char sH[2][8 * 1024];
    __shared__ int sXrow[128];

    const int tid = threadIdx.x;
    const int lane = tid & 63, wid = tid >> 6;
    const int wm = wid >> 1, wn = wid & 1;
    const int l15 = lane & 15, lhi = lane >> 4;
    const int bid = blockIdx.x;
    const int xcd = bid & 7, idx = bid >> 3;
    const int rb = xcd * 8 + (idx & 7);
    const int cb = idx >> 3;
    const int row0 = rb * 128, c0 = cb * 64;

    if (tid < 128) {
        int nn = row0 + tid;
        sXrow[tid] = (nn >> 9) * TT + ids[(size_t)nn * WW + step];
    }

    const int slot = lane & 3, lc = lane >> 2;
    const f16* bsrc[3]; int bdst[3];
#pragma unroll
    for (int ii = 0; ii < 3; ++ii) {
        int ch = wid * 3 + ii;
        int gg = ch >> 2, cg2 = ch & 3;
        int col = cg2 * 16 + lc;
        bsrc[ii] = w16 + ((size_t)(1536 + gg * 512 + c0 + col) * 512
                          + (size_t)((slot ^ ((col >> 1) & 3)) * 8));
        bdst[ii] = ch * 1024;
    }
    const f16* hsrc[2]; int hdst[2];
#pragma unroll
    for (int ii = 0; ii < 2; ++ii) {
        int ch = wid * 2 + ii;
        int hrow = ch * 16 + lc;
        hsrc[ii] = h16r + ((size_t)(row0 + hrow) * 512
                           + (size_t)((slot ^ ((lc >> 1) & 3)) * 8));
        hdst[ii] = ch * 1024;
    }

    const int swzo = (lhi ^ ((l15 >> 1) & 3)) * 16;
    const int aA0 = (wm * 64 + l15) * 64 + swzo;
    int colb[2];
#pragma unroll
    for (int nf = 0; nf < 2; ++nf)
        colb[nf] = (wn * 32 + nf * 16 + l15) * 64 + swzo;

    f32x4 accR[4][2], accZ[4][2], accHN[4][2];
#pragma unroll
    for (int mf = 0; mf < 4; ++mf)
#pragma unroll
        for (int nf = 0; nf < 2; ++nf) {
            f32x4 z = {0.f, 0.f, 0.f, 0.f};
            accR[mf][nf] = z; accZ[mf][nf] = z; accHN[mf][nf] = z;
        }

#pragma unroll
    for (int ii = 0; ii < 3; ++ii)
        __builtin_amdgcn_global_load_lds(
            (const __attribute__((address_space(1))) unsigned*)bsrc[ii],
            (__attribute__((address_space(3))) unsigned*)(&sB[0][0] + bdst[ii]), 16, 0, 0);
#pragma unroll
    for (int ii = 0; ii < 2; ++ii)
        __builtin_amdgcn_global_load_lds(
            (const __attribute__((address_space(1))) unsigned*)hsrc[ii],
            (__attribute__((address_space(3))) unsigned*)(&sH[0][0] + hdst[ii]), 16, 0, 0);

    int cur = 0;
    for (int ks = 0; ks < 16; ++ks) {
        asm volatile("s_waitcnt vmcnt(0)" ::: "memory");
        __syncthreads();

        const int kn = (ks + 1) * 32;
        if (ks < 15) {
#pragma unroll
            for (int ii = 0; ii < 3; ++ii)
                __builtin_amdgcn_global_load_lds(
                    (const __attribute__((address_space(1))) unsigned*)(bsrc[ii] + kn),
                    (__attribute__((address_space(3))) unsigned*)(&sB[cur ^ 1][0] + bdst[ii]), 16, 0, 0);
#pragma unroll
            for (int ii = 0; ii < 2; ++ii)
                __builtin_amdgcn_global_load_lds(
                    (const __attribute__((address_space(1))) unsigned*)(hsrc[ii] + kn),
                    (__attribute__((address_space(3))) unsigned*)(&sH[cur ^ 1][0] + hdst[ii]), 16, 0, 0);
        }

        f16x8 ah[4];
#pragma unroll
        for (int mf = 0; mf < 4; ++mf)
            ah[mf] = *(const f16x8*)(&sH[cur][0] + aA0 + mf * 1024);

#pragma unroll
        for (int nf = 0; nf < 2; ++nf) {
            const char* bb = &sB[cur][0] + colb[nf];
            f16x8 B0 = *(const f16x8*)(bb + 0 * 4096);
            f16x8 B1 = *(const f16x8*)(bb + 1 * 4096);
            f16x8 B2 = *(const f16x8*)(bb + 2 * 4096);
#pragma unroll
            for (int mf = 0; mf < 4; ++mf) {
                accR[mf][nf]  = MFMA16(ah[mf], B0, accR[mf][nf]);
                accZ[mf][nf]  = MFMA16(ah[mf], B1, accZ[mf][nf]);
                accHN[mf][nf] = MFMA16(ah[mf], B2, accHN[mf][nf]);
            }
        }
        cur ^= 1;
    }

#pragma unroll
    for (int nf = 0; nf < 2; ++nf) {
        int col = c0 + wn * 32 + nf * 16 + l15;
        float bhr = b_hh[col];
        float bhz = b_hh[DD + col];
        float bhn = b_hh[2 * DD + col];
#pragma unroll
        for (int mf = 0; mf < 4; ++mf) {
#pragma unroll
            for (int r = 0; r < 4; ++r) {
                int row = row0 + wm * 64 + mf * 16 + lhi * 4 + r;
                size_t off = (size_t)row * DD + col;
                int src = sXrow[row - row0];
                const f16* gr = gi + (size_t)src * 1536 + col;
                float gir = (float)gr[0];
                float giz = (float)gr[512];
                float gin = (float)gr[1024];
                float hold = (float)h16r[off];
                float R = fsigm(gir + accR[mf][nf][r] + bhr);
                float Z = fsigm(giz + accZ[mf][nf][r] + bhz);
                float N = ftanh(gin + R * (accHN[mf][nf][r] + bhn));
                float res = (1.0f - Z) * N + Z * hold;
                if (h16w) h16w[off] = (f16)res;
                if (f32w) f32w[off] = res;
            }
        }
    }
}

// ---------------------------------------------------------------------------
extern "C" void kernel_launch(void* const* d_in, const int* in_sizes, int n_in,
                              void* d_out, int out_size, void* d_ws, size_t ws_size,
                              hipStream_t stream)
{
    const float* x    = (const float*)d_in[0];
    const float* w_ih = (const float*)d_in[1];
    const float* w_hh = (const float*)d_in[2];
    const float* b_ih = (const float*)d_in[3];
    const float* b_hh = (const float*)d_in[4];

    char* ws = (char*)d_ws;
    int*  ids = (int*)(ws + WS_IDS);
    f16*  w16 = (f16*)(ws + WS_W16);
    f16*  P0  = (f16*)(ws + WS_H16);       // ping
    f16*  P1  = (f16*)d_out;               // pong (aliases d_out; last step writes f32)
    f16*  gi  = (f16*)(ws + WS_GI);
    float* fo = (float*)d_out;

    select_topk_kernel<<<dim3(NROWS / 4), dim3(256), 0, stream>>>(x, ids);
    convert_w_kernel<<<dim3(1536), dim3(256), 0, stream>>>(w_ih, w_hh, w16);
    gi_gemm_kernel<<<dim3(3072), dim3(256), 0, stream>>>(x, w16, b_ih, gi);
    step0_kernel<<<dim3(2048), dim3(256), 0, stream>>>(ids, gi, b_hh, P0);   // h1 -> P0

    const int* ids_c = ids; const f16* w16_c = w16; const f16* gi_c = gi;
    void* args[] = { (void*)&ids_c, (void*)&w16_c, (void*)&b_hh, (void*)&gi_c,
                     (void*)&P0, (void*)&P1, (void*)&fo };
    hipError_t err = hipLaunchCooperativeKernel(
        gru_steps_fused_kernel, dim3(512), dim3(256), args, 0, stream);
    if (err != hipSuccess) {
        // fallback: proven per-step launches
        for (int s = 1; s < WW; ++s) {
            const f16* hr = (s & 1) ? P0 : P1;
            f16* hw      = (s == WW - 1) ? nullptr : ((s & 1) ? P1 : P0);
            float* fw    = (s == WW - 1) ? fo : nullptr;
            gru_step_h_kernel<<<dim3(512), dim3(256), 0, stream>>>(
                ids, w16, b_hh, gi, hr, hw, fw, s);
        }
    }
}

// Round 8
// 488.060 us; speedup vs baseline: 3.5141x; 3.5141x over previous
//
#include <hip/hip_runtime.h>
#include <math.h>

// Problem constants
#define BB 16
#define TT 2048
#define DD 512
#define WW 12
#define TQ 512
#define NROWS (BB * TQ)

typedef _Float16 f16;
typedef __attribute__((ext_vector_type(8))) _Float16 f16x8;
typedef __attribute__((ext_vector_type(4))) _Float16 f16x4;
typedef __attribute__((ext_vector_type(4))) float f32x4;

#define MFMA16(a, b, c) __builtin_amdgcn_mfma_f32_16x16x32_f16((a), (b), (c), 0, 0, 0)

// ws layout
#define WS_IDS  0u
#define WS_W16  (512u * 1024u)              // 3072 x 512 f16 = 3 MB ([w_ih ; w_hh])
#define WS_H16  (4u * 1024u * 1024u)        // 8192 x 512 f16 = 8 MB (ping)
#define WS_GI   (12u * 1024u * 1024u)       // 32768 x 1536 f16 = 96 MB

__device__ __forceinline__ float fsigm(float v) { return 1.0f / (1.0f + __expf(-v)); }
__device__ __forceinline__ float ftanh(float v) {
    float a = fabsf(v);
    float t = __expf(-2.0f * a);
    float r = (1.0f - t) / (1.0f + t);
    return copysignf(r, v);
}

__device__ __forceinline__ f16x8 cvt8(float4 a, float4 b) {
    f16x8 r;
    r[0] = (_Float16)a.x; r[1] = (_Float16)a.y; r[2] = (_Float16)a.z; r[3] = (_Float16)a.w;
    r[4] = (_Float16)b.x; r[5] = (_Float16)b.y; r[6] = (_Float16)b.z; r[7] = (_Float16)b.w;
    return r;
}

// -------- Kernel 1: band top-k selection (branch-free candidate loop) -------
// 256 thr = 4 waves = 4 queries. lane = (i, c): c = lane&3 candidate stream,
// i = lane>>2 k-slice. 6 rounds x 4 candidates, rows clamped (no divergence);
// invalid candidates discarded at rank stage. fp64 accumulate (exact ranking).
__global__ __launch_bounds__(256) void select_topk_kernel(
    const float* __restrict__ x, int* __restrict__ ids)
{
    const int tid = threadIdx.x, wid = tid >> 6, lane = tid & 63;
    const int bid = blockIdx.x;
    const int swz = (bid & 7) * 256 + (bid >> 3);
    const int n = swz * 4 + wid;
    const int b = n >> 9, qi = n & 511;

    int t = (qi == TQ - 1) ? (TT - 1)
          : (int)((double)qi * ((double)(TT - 1) / (double)(TQ - 1)));
    int j0 = t - (WW - 1); if (j0 < 0) j0 = 0;
    int j1 = t + (WW - 1); if (j1 > TT - 1) j1 = TT - 1;
    const int ncand = j1 - j0 + 1;

    const int c = lane & 3, i = lane >> 2;
    const float* qrow = x + ((size_t)b * TT + t) * DD + i * 4;

    float4 q[8];
#pragma unroll
    for (int it = 0; it < 8; ++it) q[it] = *(const float4*)(qrow + it * 64);

    double s[6];
#pragma unroll
    for (int r = 0; r < 6; ++r) {
        int cc = r * 4 + c;
        int jr = j0 + cc; if (jr > j1) jr = j1;        // clamp, no branch around loads
        const float* krow = x + ((size_t)b * TT + jr) * DD + i * 4;
        double s0 = 0.0, s1 = 0.0;
#pragma unroll
        for (int it = 0; it < 8; ++it) {
            float4 kv = *(const float4*)(krow + it * 64);
            s0 = fma((double)q[it].x, (double)kv.x, s0);
            s1 = fma((double)q[it].y, (double)kv.y, s1);
            s0 = fma((double)q[it].z, (double)kv.z, s0);
            s1 = fma((double)q[it].w, (double)kv.w, s1);
        }
        double sv = s0 + s1;
        sv += __shfl_xor(sv, 4);
        sv += __shfl_xor(sv, 8);
        sv += __shfl_xor(sv, 16);
        sv += __shfl_xor(sv, 32);
        s[r] = sv;
    }

    const int rr = lane >> 2;
    double sj = s[0];
    sj = (rr == 1) ? s[1] : sj;
    sj = (rr == 2) ? s[2] : sj;
    sj = (rr == 3) ? s[3] : sj;
    sj = (rr == 4) ? s[4] : sj;
    sj = (rr == 5) ? s[5] : sj;
    bool valid = lane < ncand;
    if (!valid) sj = -1.0e300;

    int rank = 0;
    for (int kk = 0; kk < 2 * WW - 1; ++kk) {
        if (kk >= ncand) break;                        // wave-uniform
        double bs = __shfl(sj, kk);
        rank += (bs > sj || (bs == sj && kk < lane)) ? 1 : 0;
    }
    bool sel = valid && (rank < WW);
    unsigned long long m = __ballot(sel);
    if (sel) {
        int pos = __popcll(m & ((1ull << lane) - 1ull));
        ids[(size_t)n * WW + pos] = j0 + lane;
    }
}

// -------- Kernel 2: f32 -> f16 weight conversion ---------------------------
__global__ __launch_bounds__(256) void convert_w_kernel(
    const float* __restrict__ wi, const float* __restrict__ wh, f16* __restrict__ w16)
{
    const int PER = 3 * DD * DD / 4;
    int i = blockIdx.x * 256 + threadIdx.x;
    float4 v;
    if (i < PER) v = ((const float4*)wi)[i];
    else         v = ((const float4*)wh)[i - PER];
    f16x4 o;
    o[0] = (_Float16)v.x; o[1] = (_Float16)v.y; o[2] = (_Float16)v.z; o[3] = (_Float16)v.w;
    *(f16x4*)(w16 + (size_t)i * 4) = o;
}

// -------- Kernel 3: GI = x @ w_ih.T + b_ih (round-7 proven, ~60us) ---------
__global__ __launch_bounds__(256, 2) void gi_gemm_kernel(
    const float* __restrict__ x,
    const f16* __restrict__ w16,        // rows 0..1535 = w_ih
    const float* __restrict__ b_ih,
    f16* __restrict__ gi)               // [32768][1536]
{
    __shared__ __align__(16) char sB[2][16 * 1024];
    __shared__ __align__(16) char sX[2][16 * 1024];

    const int tid = threadIdx.x;
    const int lane = tid & 63, wid = tid >> 6;
    const int wm = wid >> 1, wn = wid & 1;
    const int l15 = lane & 15, lhi = lane >> 4;
    const int bid = blockIdx.x;
    const int xcd = bid & 7, idx = bid >> 3;
    const int rb = xcd * 32 + idx / 12;
    const int cb = idx % 12;
    const int row0 = rb * 128, c0 = cb * 128;

    const int slot = lane & 3, lc = lane >> 2;
    const f16* bsrc[4]; int bdst[4];
#pragma unroll
    for (int ii = 0; ii < 4; ++ii) {
        int ch = wid * 4 + ii;
        int half = ch >> 3, cg = ch & 7;
        int col = cg * 16 + lc;
        bsrc[ii] = w16 + ((size_t)(c0 + col) * 512 + half * 32
                          + (size_t)((slot ^ ((col >> 1) & 3)) * 8));
        bdst[ii] = half * 8192 + cg * 1024;
    }

    const int xrow = tid >> 1, bsel = tid & 1;
    const int cA = (2 * bsel) ^ ((xrow >> 1) & 3);
    const float* xsrc = x + (size_t)(row0 + xrow) * DD;
    const float* xp0 = xsrc + cA * 8;
    const float* xp1 = xsrc + (cA ^ 1) * 8;
    const int xw0 = xrow * 64 + (2 * bsel) * 16;

    const int swzo = (lhi ^ ((l15 >> 1) & 3)) * 16;
    const int aBase = (wm * 64 + l15) * 64 + swzo;
    const int bBase = (wn * 64 + l15) * 64 + swzo;

    f32x4 acc[4][4];
#pragma unroll
    for (int mf = 0; mf < 4; ++mf)
#pragma unroll
        for (int nf = 0; nf < 4; ++nf) { f32x4 z = {0.f,0.f,0.f,0.f}; acc[mf][nf] = z; }

    {
#pragma unroll
        for (int ii = 0; ii < 4; ++ii)
            __builtin_amdgcn_global_load_lds(
                (const __attribute__((address_space(1))) unsigned*)bsrc[ii],
                (__attribute__((address_space(3))) unsigned*)(&sB[0][0] + bdst[ii]), 16, 0, 0);
#pragma unroll
        for (int h = 0; h < 2; ++h) {
            float4 a0 = *(const float4*)(xp0 + h * 32);
            float4 a1 = *(const float4*)(xp0 + h * 32 + 4);
            float4 a2 = *(const float4*)(xp1 + h * 32);
            float4 a3 = *(const float4*)(xp1 + h * 32 + 4);
            *(f16x8*)(&sX[0][0] + h * 8192 + xw0)      = cvt8(a0, a1);
            *(f16x8*)(&sX[0][0] + h * 8192 + xw0 + 16) = cvt8(a2, a3);
        }
    }

    int cur = 0;
    for (int ks = 0; ks < 8; ++ks) {
        asm volatile("s_waitcnt vmcnt(0)" ::: "memory");
        __syncthreads();

        const int kn = (ks + 1) * 64;
        float4 a[2][4];
        if (ks < 7) {
#pragma unroll
            for (int ii = 0; ii < 4; ++ii)
                __builtin_amdgcn_global_load_lds(
                    (const __attribute__((address_space(1))) unsigned*)(bsrc[ii] + kn),
                    (__attribute__((address_space(3))) unsigned*)(&sB[cur ^ 1][0] + bdst[ii]), 16, 0, 0);
#pragma unroll
            for (int h = 0; h < 2; ++h) {
                a[h][0] = *(const float4*)(xp0 + kn + h * 32);
                a[h][1] = *(const float4*)(xp0 + kn + h * 32 + 4);
                a[h][2] = *(const float4*)(xp1 + kn + h * 32);
                a[h][3] = *(const float4*)(xp1 + kn + h * 32 + 4);
            }
        }

#pragma unroll
        for (int h = 0; h < 2; ++h) {
            f16x8 ax[4];
#pragma unroll
            for (int mf = 0; mf < 4; ++mf)
                ax[mf] = *(const f16x8*)(&sX[cur][0] + h * 8192 + aBase + mf * 1024);
#pragma unroll
            for (int nf = 0; nf < 4; ++nf) {
                f16x8 Bv = *(const f16x8*)(&sB[cur][0] + h * 8192 + bBase + nf * 1024);
#pragma unroll
                for (int mf = 0; mf < 4; ++mf)
                    acc[mf][nf] = MFMA16(ax[mf], Bv, acc[mf][nf]);
            }
        }

        if (ks < 7) {
#pragma unroll
            for (int h = 0; h < 2; ++h) {
                *(f16x8*)(&sX[cur ^ 1][0] + h * 8192 + xw0)      = cvt8(a[h][0], a[h][1]);
                *(f16x8*)(&sX[cur ^ 1][0] + h * 8192 + xw0 + 16) = cvt8(a[h][2], a[h][3]);
            }
        }
        cur ^= 1;
    }

#pragma unroll
    for (int nf = 0; nf < 4; ++nf) {
        int col = c0 + wn * 64 + nf * 16 + l15;
        float bi = b_ih[col];
#pragma unroll
        for (int mf = 0; mf < 4; ++mf)
#pragma unroll
            for (int r = 0; r < 4; ++r) {
                int row = row0 + wm * 64 + mf * 16 + lhi * 4 + r;
                gi[(size_t)row * 1536 + col] = (f16)(acc[mf][nf][r] + bi);
            }
    }
}

// -------- Kernel 4: step 0 elementwise (h0 = 0) ----------------------------
__global__ __launch_bounds__(256) void step0_kernel(
    const int* __restrict__ ids, const f16* __restrict__ gi,
    const float* __restrict__ b_hh, f16* __restrict__ h16w)
{
    int g = blockIdx.x * 256 + threadIdx.x;
    int row = g >> 6;
    int c8 = (g & 63) * 8;
    int src = (row >> 9) * TT + ids[(size_t)row * WW + 0];
    const f16* gr = gi + (size_t)src * 1536 + c8;
    f16x8 vr = *(const f16x8*)(gr);
    f16x8 vz = *(const f16x8*)(gr + 512);
    f16x8 vn = *(const f16x8*)(gr + 1024);
    f16x8 out;
#pragma unroll
    for (int j = 0; j < 8; ++j) {
        int col = c8 + j;
        float R = fsigm((float)vr[j] + b_hh[col]);
        float Z = fsigm((float)vz[j] + b_hh[DD + col]);
        float N = ftanh((float)vn[j] + R * b_hh[2 * DD + col]);
        out[j] = (f16)((1.0f - Z) * N);
    }
    *(f16x8*)(h16w + (size_t)row * DD + c8) = out;
}

// -------- Kernel 5: h-side GRU step, BK=64, 8 phases -----------------------
// 256 thr / 4 waves; tile 128 rows x 64 cols; grid 512 = 64 rb x 8 cb.
// LDS exactly 80 KB (2 blocks/CU): B 2x24KB [gate3][col64][128B], h 2x16KB
// [row128][128B]; both 8-slot rows with slot ^= (entity&7) swizzle, staged
// via pre-swizzled-source global_load_lds. 48 MFMA/wave/phase.
__global__ __launch_bounds__(256, 2) void gru_step_h_kernel(
    const int* __restrict__ ids,
    const f16* __restrict__ w16,        // rows 1536..3071 = w_hh
    const float* __restrict__ b_hh,
    const f16* __restrict__ gi,
    const f16* __restrict__ h16r,
    f16* __restrict__ h16w,
    float* __restrict__ f32w,
    int step)
{
    __shared__ __align__(16) char sB[2][24 * 1024];
    __shared__ __align__(16) char sH[2][16 * 1024];

    const int tid = threadIdx.x;
    const int lane = tid & 63, wid = tid >> 6;
    const int wm = wid >> 1, wn = wid & 1;
    const int l15 = lane & 15, lhi = lane >> 4;
    const int bid = blockIdx.x;
    const int xcd = bid & 7, idx = bid >> 3;
    const int rb = xcd * 8 + (idx & 7);
    const int cb = idx >> 3;
    const int row0 = rb * 128, c0 = cb * 64;

    // staging lane decomposition: row_local = lane>>3, slot = lane&7
    const int lrow = lane >> 3, lslot = lane & 7;
    const int sswz = (lslot ^ lrow) * 8;           // source k-element offset term

    // B: 6 chunks/wave (24 total); chunk = 8 cols x 8 slots = 1KB
    const f16* bsrc[6]; int bdst[6];
#pragma unroll
    for (int ii = 0; ii < 6; ++ii) {
        int ch = wid * 6 + ii;                     // 0..23
        int gate = ch >> 3, cg = ch & 7;
        int col = cg * 8 + lrow;
        bsrc[ii] = w16 + ((size_t)(1536 + gate * 512 + c0 + col) * 512 + sswz);
        bdst[ii] = gate * 8192 + cg * 1024 + lrow * 128 + lslot * 16;
    }
    // h: 4 chunks/wave (16 total); chunk = 8 rows x 8 slots = 1KB
    const f16* hsrc[4]; int hdst[4];
#pragma unroll
    for (int ii = 0; ii < 4; ++ii) {
        int ch = wid * 4 + ii;                     // 0..15
        int hrow = ch * 8 + lrow;
        hsrc[ii] = h16r + ((size_t)(row0 + hrow) * 512 + sswz);
        hdst[ii] = ch * 1024 + lrow * 128 + lslot * 16;
    }

    // fragment read offsets
    const int rowrd = wm * 64 + l15;               // + mf*16
    const int colrd = wn * 32 + l15;               // + nf*16
    int aOff[4][2], bOff[2][2];                    // [mf][half], [nf][half] (gate stride 8192)
#pragma unroll
    for (int mf = 0; mf < 4; ++mf)
#pragma unroll
        for (int h = 0; h < 2; ++h) {
            int rr = rowrd + mf * 16;
            aOff[mf][h] = rr * 128 + ((((h << 2) | lhi) ^ (rr & 7)) << 4);
        }
#pragma unroll
    for (int nf = 0; nf < 2; ++nf)
#pragma unroll
        for (int h = 0; h < 2; ++h) {
            int cc = colrd + nf * 16;
            bOff[nf][h] = cc * 128 + ((((h << 2) | lhi) ^ (cc & 7)) << 4);
        }

    f32x4 accR[4][2], accZ[4][2], accHN[4][2];
#pragma unroll
    for (int mf = 0; mf < 4; ++mf)
#pragma unroll
        for (int nf = 0; nf < 2; ++nf) {
            f32x4 z = {0.f, 0.f, 0.f, 0.f};
            accR[mf][nf] = z; accZ[mf][nf] = z; accHN[mf][nf] = z;
        }

    // prologue: fill buffer 0 (k0 = 0)
#pragma unroll
    for (int ii = 0; ii < 6; ++ii)
        __builtin_amdgcn_global_load_lds(
            (const __attribute__((address_space(1))) unsigned*)bsrc[ii],
            (__attribute__((address_space(3))) unsigned*)(&sB[0][0] + bdst[ii]), 16, 0, 0);
#pragma unroll
    for (int ii = 0; ii < 4; ++ii)
        __builtin_amdgcn_global_load_lds(
            (const __attribute__((address_space(1))) unsigned*)hsrc[ii],
            (__attribute__((address_space(3))) unsigned*)(&sH[0][0] + hdst[ii]), 16, 0, 0);

    int cur = 0;
    for (int ks = 0; ks < 8; ++ks) {
        asm volatile("s_waitcnt vmcnt(0)" ::: "memory");
        __syncthreads();

        const int kn = (ks + 1) * 64;
        if (ks < 7) {
#pragma unroll
            for (int ii = 0; ii < 6; ++ii)
                __builtin_amdgcn_global_load_lds(
                    (const __attribute__((address_space(1))) unsigned*)(bsrc[ii] + kn),
                    (__attribute__((address_space(3))) unsigned*)(&sB[cur ^ 1][0] + bdst[ii]), 16, 0, 0);
#pragma unroll
            for (int ii = 0; ii < 4; ++ii)
                __builtin_amdgcn_global_load_lds(
                    (const __attribute__((address_space(1))) unsigned*)(hsrc[ii] + kn),
                    (__attribute__((address_space(3))) unsigned*)(&sH[cur ^ 1][0] + hdst[ii]), 16, 0, 0);
        }

#pragma unroll
        for (int h = 0; h < 2; ++h) {
            f16x8 ah[4];
#pragma unroll
            for (int mf = 0; mf < 4; ++mf)
                ah[mf] = *(const f16x8*)(&sH[cur][0] + aOff[mf][h]);
#pragma unroll
            for (int nf = 0; nf < 2; ++nf) {
                const char* bb = &sB[cur][0] + bOff[nf][h];
                f16x8 B0 = *(const f16x8*)(bb + 0 * 8192);
                f16x8 B1 = *(const f16x8*)(bb + 1 * 8192);
                f16x8 B2 = *(const f16x8*)(bb + 2 * 8192);
#pragma unroll
                for (int mf = 0; mf < 4; ++mf) {
                    accR[mf][nf]  = MFMA16(ah[mf], B0, accR[mf][nf]);
                    accZ[mf][nf]  = MFMA16(ah[mf], B1, accZ[mf][nf]);
                    accHN[mf][nf] = MFMA16(ah[mf], B2, accHN[mf][nf]);
                }
            }
        }
        cur ^= 1;
    }

    // epilogue: gather GI, gates, state update
#pragma unroll
    for (int nf = 0; nf < 2; ++nf) {
        int col = c0 + wn * 32 + nf * 16 + l15;
        float bhr = b_hh[col];
        float bhz = b_hh[DD + col];
        float bhn = b_hh[2 * DD + col];
#pragma unroll
        for (int mf = 0; mf < 4; ++mf) {
#pragma unroll
            for (int r = 0; r < 4; ++r) {
                int row = row0 + wm * 64 + mf * 16 + lhi * 4 + r;
                size_t off = (size_t)row * DD + col;
                int src = (row >> 9) * TT + ids[(size_t)row * WW + step];
                const f16* gr = gi + (size_t)src * 1536 + col;
                float gir = (float)gr[0];
                float giz = (float)gr[512];
                float gin = (float)gr[1024];
                float hold = (float)h16r[off];
                float R = fsigm(gir + accR[mf][nf][r] + bhr);
                float Z = fsigm(giz + accZ[mf][nf][r] + bhz);
                float N = ftanh(gin + R * (accHN[mf][nf][r] + bhn));
                float res = (1.0f - Z) * N + Z * hold;
                if (h16w) h16w[off] = (f16)res;
                if (f32w) f32w[off] = res;
            }
        }
    }
}

// ---------------------------------------------------------------------------
extern "C" void kernel_launch(void* const* d_in, const int* in_sizes, int n_in,
                              void* d_out, int out_size, void* d_ws, size_t ws_size,
                              hipStream_t stream)
{
    const float* x    = (const float*)d_in[0];
    const float* w_ih = (const float*)d_in[1];
    const float* w_hh = (const float*)d_in[2];
    const float* b_ih = (const float*)d_in[3];
    const float* b_hh = (const float*)d_in[4];

    char* ws = (char*)d_ws;
    int*  ids = (int*)(ws + WS_IDS);
    f16*  w16 = (f16*)(ws + WS_W16);
    f16*  P0  = (f16*)(ws + WS_H16);       // ping
    f16*  P1  = (f16*)d_out;               // pong (aliases d_out; last step writes f32)
    f16*  gi  = (f16*)(ws + WS_GI);
    float* fo = (float*)d_out;

    select_topk_kernel<<<dim3(NROWS / 4), dim3(256), 0, stream>>>(x, ids);
    convert_w_kernel<<<dim3(1536), dim3(256), 0, stream>>>(w_ih, w_hh, w16);
    gi_gemm_kernel<<<dim3(3072), dim3(256), 0, stream>>>(x, w16, b_ih, gi);
    step0_kernel<<<dim3(2048), dim3(256), 0, stream>>>(ids, gi, b_hh, P0);   // h1 -> P0

    for (int s = 1; s < WW; ++s) {
        const f16* hr = (s & 1) ? P0 : P1;
        f16* hw      = (s == WW - 1) ? nullptr : ((s & 1) ? P1 : P0);
        float* fw    = (s == WW - 1) ? fo : nullptr;
        gru_step_h_kernel<<<dim3(512), dim3(256), 0, stream>>>(
            ids, w16, b_hh, gi, hr, hw, fw, s);
    }
}